// Round 1
// baseline (566.509 us; speedup 1.0000x reference)
//
#include <hip/hip_runtime.h>

// GCNConv: out = scatter_add(norm * (x@W)[row] -> col) + b, with self-loops
// and symmetric degree normalization.
constexpr int N_NODES = 100000;
constexpr int IN_F    = 128;
constexpr int OUT_F   = 64;
constexpr int N_EDGES = 1600000;

// ---------------------------------------------------------------- degree ----
__global__ __launch_bounds__(256) void deg_kernel(const int* __restrict__ col,
                                                  float* __restrict__ deg) {
    int i = blockIdx.x * blockDim.x + threadIdx.x;
    int stride = gridDim.x * blockDim.x;
    for (int e = i; e < N_EDGES; e += stride)
        atomicAdd(&deg[col[e]], 1.0f);
}

// deg -> deg^{-1/2} in place (self-loop adds +1, so always > 0)
__global__ __launch_bounds__(256) void dis_kernel(float* __restrict__ deg_dis) {
    int i = blockIdx.x * blockDim.x + threadIdx.x;
    if (i < N_NODES) deg_dis[i] = rsqrtf(deg_dis[i] + 1.0f);
}

// ---------------------------------------------------------------- h = x@W ---
// Block: 256 threads, 32 rows/block. W (128x64, 32KB) + X tile (32x128, 16KB)
// in LDS. Thread t computes col = t&63 for rows (t>>6) + 4*j, j=0..7.
// Xs reads are wave-uniform (broadcast, conflict-free); Ws reads are 64
// consecutive floats (2 lanes/bank = free).
constexpr int GEMM_ROWS = 32;
__global__ __launch_bounds__(256) void gemm_kernel(const float* __restrict__ x,
                                                   const float* __restrict__ W,
                                                   float* __restrict__ h) {
    __shared__ float Ws[IN_F][OUT_F];       // 32 KB
    __shared__ float Xs[GEMM_ROWS][IN_F];   // 16 KB
    const int tid = threadIdx.x;

    for (int i = tid; i < IN_F * OUT_F / 4; i += 256)
        ((float4*)Ws)[i] = ((const float4*)W)[i];

    const int row0 = blockIdx.x * GEMM_ROWS;
    for (int i = tid; i < GEMM_ROWS * IN_F / 4; i += 256)
        ((float4*)Xs)[i] = ((const float4*)(x + (long)row0 * IN_F))[i];

    __syncthreads();

    const int colc  = tid & 63;
    const int rbase = tid >> 6;  // 0..3, wave-uniform
    float acc[8];
#pragma unroll
    for (int j = 0; j < 8; ++j) acc[j] = 0.0f;

    for (int k = 0; k < IN_F; ++k) {
        float w = Ws[k][colc];
#pragma unroll
        for (int j = 0; j < 8; ++j)
            acc[j] += Xs[rbase + 4 * j][k] * w;
    }

#pragma unroll
    for (int j = 0; j < 8; ++j) {
        int r = rbase + 4 * j;
        h[(long)(row0 + r) * OUT_F + colc] = acc[j];
    }
}

// ------------------------------------------------- out = b + dis^2 * h -----
__global__ __launch_bounds__(256) void selfloop_kernel(const float* __restrict__ h,
                                                       const float* __restrict__ dis,
                                                       const float* __restrict__ b,
                                                       float* __restrict__ out) {
    int i = blockIdx.x * blockDim.x + threadIdx.x;
    int stride = gridDim.x * blockDim.x;
    const int total = N_NODES * OUT_F / 4;  // float4 elements
    for (int idx = i; idx < total; idx += stride) {
        int node = idx >> 4;          // 16 float4 per node (OUT_F=64)
        int c4   = idx & 15;
        float s  = dis[node];
        s = s * s;
        float4 hv = ((const float4*)h)[idx];
        float4 bv = ((const float4*)b)[c4];
        float4 o;
        o.x = bv.x + s * hv.x;
        o.y = bv.y + s * hv.y;
        o.z = bv.z + s * hv.z;
        o.w = bv.w + s * hv.w;
        ((float4*)out)[idx] = o;
    }
}

// -------------------------------------------------------- edge scatter -----
// One wave (64 lanes) per edge: lane c handles output feature c. Gather and
// atomic bursts are 256B contiguous per edge.
__global__ __launch_bounds__(256) void scatter_kernel(const int* __restrict__ eidx,
                                                      const float* __restrict__ dis,
                                                      const float* __restrict__ h,
                                                      float* __restrict__ out) {
    int gtid = blockIdx.x * blockDim.x + threadIdx.x;
    int wid  = gtid >> 6;
    int lane = threadIdx.x & 63;
    int nw   = (gridDim.x * blockDim.x) >> 6;
    for (int e = wid; e < N_EDGES; e += nw) {
        int row = eidx[e];
        int col = eidx[N_EDGES + e];
        float norm = dis[row] * dis[col];
        atomicAdd(&out[(long)col * OUT_F + lane],
                  norm * h[(long)row * OUT_F + lane]);
    }
}

// ---------------------------------------------------------------------------
extern "C" void kernel_launch(void* const* d_in, const int* in_sizes, int n_in,
                              void* d_out, int out_size, void* d_ws, size_t ws_size,
                              hipStream_t stream) {
    const float* x   = (const float*)d_in[0];
    const int*   idx = (const int*)d_in[1];   // [2, E] int32 per harness doc
    const float* W   = (const float*)d_in[2];
    const float* b   = (const float*)d_in[3];
    float*       out = (float*)d_out;

    float* deg_dis = (float*)d_ws;            // N floats (deg, then dis in place)
    float* h       = deg_dis + N_NODES;       // N*OUT_F floats

    hipMemsetAsync(d_ws, 0, N_NODES * sizeof(float), stream);
    deg_kernel<<<2048, 256, 0, stream>>>(idx + N_EDGES, deg_dis);
    dis_kernel<<<(N_NODES + 255) / 256, 256, 0, stream>>>(deg_dis);
    gemm_kernel<<<N_NODES / GEMM_ROWS, 256, 0, stream>>>(x, W, h);
    selfloop_kernel<<<2048, 256, 0, stream>>>(h, deg_dis, b, out);
    scatter_kernel<<<4096, 256, 0, stream>>>(idx, deg_dis, h, out);
}

// Round 3
// 499.750 us; speedup vs baseline: 1.1336x; 1.1336x over previous
//
#include <hip/hip_runtime.h>

// GCNConv: out = segment_sum(norm * (x@W)[row] -> col) + b, self-loops +
// symmetric degree normalization. Gather formulation (CSR built per call)
// to avoid 102M f32 global atomics (round-1 profile: 400MB atomic
// write-through at EA was the bottleneck).
constexpr int N_NODES = 100000;
constexpr int IN_F    = 128;
constexpr int OUT_F   = 64;
constexpr int N_EDGES = 1600000;
constexpr int SCAN_B  = 256;                       // elems per scan block
constexpr int N_SCANB = (N_NODES + SCAN_B - 1) / SCAN_B;  // 391

// ------------------------------------------------------------- in-degree ---
__global__ __launch_bounds__(256) void count_kernel(const int* __restrict__ col,
                                                    int* __restrict__ cnt) {
    int i = blockIdx.x * blockDim.x + threadIdx.x;
    int stride = gridDim.x * blockDim.x;
    for (int e = i; e < N_EDGES; e += stride)
        atomicAdd(&cnt[col[e]], 1);
}

// dis[i] = rsqrt(deg_i + 1)   (+1 = self loop, so never zero)
__global__ __launch_bounds__(256) void dis_kernel(const int* __restrict__ cnt,
                                                  float* __restrict__ dis) {
    int i = blockIdx.x * blockDim.x + threadIdx.x;
    if (i < N_NODES) dis[i] = rsqrtf((float)cnt[i] + 1.0f);
}

// --------------------------------------------- exclusive scan (3 kernels) --
__global__ __launch_bounds__(SCAN_B) void scanA_kernel(const int* __restrict__ cnt,
                                                       int* __restrict__ scanned,
                                                       int* __restrict__ bsum) {
    __shared__ int s[SCAN_B];
    int i = blockIdx.x * SCAN_B + threadIdx.x;
    int v = (i < N_NODES) ? cnt[i] : 0;
    s[threadIdx.x] = v;
    __syncthreads();
#pragma unroll
    for (int off = 1; off < SCAN_B; off <<= 1) {
        int t = (threadIdx.x >= off) ? s[threadIdx.x - off] : 0;
        __syncthreads();
        s[threadIdx.x] += t;
        __syncthreads();
    }
    if (i < N_NODES) scanned[i] = s[threadIdx.x] - v;   // exclusive
    if (threadIdx.x == SCAN_B - 1) bsum[blockIdx.x] = s[SCAN_B - 1];
}

__global__ __launch_bounds__(512) void scanB_kernel(int* __restrict__ bsum,
                                                    int* __restrict__ bscan) {
    __shared__ int s[512];
    int v = (threadIdx.x < N_SCANB) ? bsum[threadIdx.x] : 0;
    s[threadIdx.x] = v;
    __syncthreads();
#pragma unroll
    for (int off = 1; off < 512; off <<= 1) {
        int t = (threadIdx.x >= off) ? s[threadIdx.x - off] : 0;
        __syncthreads();
        s[threadIdx.x] += t;
        __syncthreads();
    }
    if (threadIdx.x < N_SCANB) bscan[threadIdx.x] = s[threadIdx.x] - v;
}

__global__ __launch_bounds__(256) void scanC_kernel(const int* __restrict__ scanned,
                                                    const int* __restrict__ bscan,
                                                    int* __restrict__ offsets,
                                                    int* __restrict__ cursor) {
    int i = blockIdx.x * blockDim.x + threadIdx.x;
    if (i < N_NODES) {
        int off = scanned[i] + bscan[i / SCAN_B];
        offsets[i] = off;
        cursor[i]  = off;
    }
    if (i == 0) offsets[N_NODES] = N_EDGES;
}

// ------------------------------------------------------------- CSR fill ----
__global__ __launch_bounds__(256) void fill_kernel(const int* __restrict__ eidx,
                                                   int* __restrict__ cursor,
                                                   int* __restrict__ sorted_row) {
    int i = blockIdx.x * blockDim.x + threadIdx.x;
    int stride = gridDim.x * blockDim.x;
    for (int e = i; e < N_EDGES; e += stride) {
        int row = eidx[e];
        int col = eidx[N_EDGES + e];
        int p = atomicAdd(&cursor[col], 1);
        sorted_row[p] = row;
    }
}

// ---------------------------------------------------------------- h = x@W --
// 256 thr / 32 rows per block. W (32KB) + X tile (16KB) in LDS. float4 LDS
// reads along k: 12 LDS instrs per 4 k-steps (vs 36 scalar).
constexpr int GEMM_ROWS = 32;
__global__ __launch_bounds__(256) void gemm_kernel(const float* __restrict__ x,
                                                   const float* __restrict__ W,
                                                   float* __restrict__ h) {
    __shared__ float Ws[IN_F][OUT_F];       // 32 KB
    __shared__ float Xs[GEMM_ROWS][IN_F];   // 16 KB
    const int tid = threadIdx.x;

    for (int i = tid; i < IN_F * OUT_F / 4; i += 256)
        ((float4*)Ws)[i] = ((const float4*)W)[i];

    const int row0 = blockIdx.x * GEMM_ROWS;
    for (int i = tid; i < GEMM_ROWS * IN_F / 4; i += 256)
        ((float4*)Xs)[i] = ((const float4*)(x + (long)row0 * IN_F))[i];

    __syncthreads();

    const int colc  = tid & 63;
    const int rbase = tid >> 6;  // 0..3, wave-uniform
    float acc[8];
#pragma unroll
    for (int j = 0; j < 8; ++j) acc[j] = 0.0f;

    for (int k = 0; k < IN_F; k += 4) {
        float w0 = Ws[k + 0][colc];
        float w1 = Ws[k + 1][colc];
        float w2 = Ws[k + 2][colc];
        float w3 = Ws[k + 3][colc];
#pragma unroll
        for (int j = 0; j < 8; ++j) {
            float4 xv = *(const float4*)&Xs[rbase + 4 * j][k];
            acc[j] += xv.x * w0 + xv.y * w1 + xv.z * w2 + xv.w * w3;
        }
    }

#pragma unroll
    for (int j = 0; j < 8; ++j)
        h[(long)(row0 + rbase + 4 * j) * OUT_F + colc] = acc[j];
}

// ------------------------------------------------------ gather + epilogue --
// One wave per target node; lane c = output feature c. Registers accumulate,
// out written exactly once (bias + self-loop fused). No f32 atomics.
__global__ __launch_bounds__(256) void gather_kernel(const int* __restrict__ sorted_row,
                                                     const int* __restrict__ offsets,
                                                     const float* __restrict__ dis,
                                                     const float* __restrict__ h,
                                                     const float* __restrict__ b,
                                                     float* __restrict__ out) {
    int gtid = blockIdx.x * blockDim.x + threadIdx.x;
    int node = gtid >> 6;
    int lane = threadIdx.x & 63;
    if (node >= N_NODES) return;

    int beg = offsets[node];
    int end = offsets[node + 1];
    float dc = dis[node];
    float acc = 0.0f;
    for (int i = beg; i < end; ++i) {
        int row = sorted_row[i];                  // wave-uniform
        acc += (dis[row] * dc) * h[(long)row * OUT_F + lane];
    }
    out[(long)node * OUT_F + lane] =
        acc + b[lane] + (dc * dc) * h[(long)node * OUT_F + lane];
}

// ---------------------------------------------------------------------------
extern "C" void kernel_launch(void* const* d_in, const int* in_sizes, int n_in,
                              void* d_out, int out_size, void* d_ws, size_t ws_size,
                              hipStream_t stream) {
    const float* x   = (const float*)d_in[0];
    const int*   idx = (const int*)d_in[1];   // [2, E], harness delivers int32
    const float* W   = (const float*)d_in[2];
    const float* b   = (const float*)d_in[3];
    float*       out = (float*)d_out;

    // workspace layout (all 4B elems)
    int*   cnt        = (int*)d_ws;                     // N
    float* dis        = (float*)(cnt + N_NODES);        // N
    int*   offsets    = (int*)(dis + N_NODES);          // N+1 (pad to N+4)
    int*   cursor     = offsets + N_NODES + 4;          // N
    int*   bsums      = cursor + N_NODES;               // 392
    int*   bscan      = bsums + 392;                    // 392
    int*   scanned    = bscan + 392;                    // N
    int*   sorted_row = scanned + N_NODES;              // E
    float* h          = (float*)(sorted_row + N_EDGES); // N*OUT_F (16B-aligned)

    hipMemsetAsync(cnt, 0, N_NODES * sizeof(int), stream);
    count_kernel<<<2048, 256, 0, stream>>>(idx + N_EDGES, cnt);
    dis_kernel<<<(N_NODES + 255) / 256, 256, 0, stream>>>(cnt, dis);
    scanA_kernel<<<N_SCANB, SCAN_B, 0, stream>>>(cnt, scanned, bsums);
    scanB_kernel<<<1, 512, 0, stream>>>(bsums, bscan);
    scanC_kernel<<<(N_NODES + 255) / 256, 256, 0, stream>>>(scanned, bscan,
                                                            offsets, cursor);
    fill_kernel<<<2048, 256, 0, stream>>>(idx, cursor, sorted_row);
    gemm_kernel<<<N_NODES / GEMM_ROWS, 256, 0, stream>>>(x, W, h);
    gather_kernel<<<(N_NODES * 64 + 255) / 256, 256, 0, stream>>>(
        sorted_row, offsets, dis, h, b, out);
}

// Round 5
// 398.333 us; speedup vs baseline: 1.4222x; 1.2546x over previous
//
#include <hip/hip_runtime.h>
#include <hip/hip_bf16.h>

// GCNConv, gather formulation + bf16 h + MFMA gemm.
// Round-1: scatter atomics (400MB EA write-through) -> gather CSR.  566->500us
// Round-4: h in bf16 (halves gather fetch), gemm via mfma_f32_16x16x32_bf16.
constexpr int N_NODES = 100000;
constexpr int IN_F    = 128;
constexpr int OUT_F   = 64;
constexpr int N_EDGES = 1600000;
constexpr int SCAN_B  = 256;
constexpr int N_SCANB = (N_NODES + SCAN_B - 1) / SCAN_B;  // 391

typedef short bf16x8 __attribute__((ext_vector_type(8)));
typedef float f32x4  __attribute__((ext_vector_type(4)));

static __device__ __forceinline__ unsigned short f2b(float f) {
    __hip_bfloat16 h = __float2bfloat16(f);
    return *reinterpret_cast<unsigned short*>(&h);
}
static __device__ __forceinline__ float blo(unsigned int u) {  // low bf16 -> f32
    return __uint_as_float(u << 16);
}
static __device__ __forceinline__ float bhi(unsigned int u) {  // high bf16 -> f32
    return __uint_as_float(u & 0xffff0000u);
}

// ------------------------------------------------------------- in-degree ---
__global__ __launch_bounds__(256) void count_kernel(const int* __restrict__ col,
                                                    int* __restrict__ cnt) {
    int i = blockIdx.x * blockDim.x + threadIdx.x;
    int stride = gridDim.x * blockDim.x;
    for (int e = i; e < N_EDGES; e += stride)
        atomicAdd(&cnt[col[e]], 1);
}

__global__ __launch_bounds__(256) void dis_kernel(const int* __restrict__ cnt,
                                                  float* __restrict__ dis) {
    int i = blockIdx.x * blockDim.x + threadIdx.x;
    if (i < N_NODES) dis[i] = rsqrtf((float)cnt[i] + 1.0f);
}

// --------------------------------------------- exclusive scan (3 kernels) --
__global__ __launch_bounds__(SCAN_B) void scanA_kernel(const int* __restrict__ cnt,
                                                       int* __restrict__ scanned,
                                                       int* __restrict__ bsum) {
    __shared__ int s[SCAN_B];
    int i = blockIdx.x * SCAN_B + threadIdx.x;
    int v = (i < N_NODES) ? cnt[i] : 0;
    s[threadIdx.x] = v;
    __syncthreads();
#pragma unroll
    for (int off = 1; off < SCAN_B; off <<= 1) {
        int t = (threadIdx.x >= off) ? s[threadIdx.x - off] : 0;
        __syncthreads();
        s[threadIdx.x] += t;
        __syncthreads();
    }
    if (i < N_NODES) scanned[i] = s[threadIdx.x] - v;   // exclusive
    if (threadIdx.x == SCAN_B - 1) bsum[blockIdx.x] = s[SCAN_B - 1];
}

__global__ __launch_bounds__(512) void scanB_kernel(int* __restrict__ bsum,
                                                    int* __restrict__ bscan) {
    __shared__ int s[512];
    int v = (threadIdx.x < N_SCANB) ? bsum[threadIdx.x] : 0;
    s[threadIdx.x] = v;
    __syncthreads();
#pragma unroll
    for (int off = 1; off < 512; off <<= 1) {
        int t = (threadIdx.x >= off) ? s[threadIdx.x - off] : 0;
        __syncthreads();
        s[threadIdx.x] += t;
        __syncthreads();
    }
    if (threadIdx.x < N_SCANB) bscan[threadIdx.x] = s[threadIdx.x] - v;
}

__global__ __launch_bounds__(256) void scanC_kernel(const int* __restrict__ scanned,
                                                    const int* __restrict__ bscan,
                                                    int* __restrict__ offsets,
                                                    int* __restrict__ cursor) {
    int i = blockIdx.x * blockDim.x + threadIdx.x;
    if (i < N_NODES) {
        int off = scanned[i] + bscan[i / SCAN_B];
        offsets[i] = off;
        cursor[i]  = off;
    }
    if (i == 0) offsets[N_NODES] = N_EDGES;
}

// ------------------------------------------------------------- CSR fill ----
__global__ __launch_bounds__(256) void fill_kernel(const int* __restrict__ eidx,
                                                   int* __restrict__ cursor,
                                                   int* __restrict__ sorted_row) {
    int i = blockIdx.x * blockDim.x + threadIdx.x;
    int stride = gridDim.x * blockDim.x;
    for (int e = i; e < N_EDGES; e += stride) {
        int row = eidx[e];
        int col = eidx[N_EDGES + e];
        int p = atomicAdd(&cursor[col], 1);
        sorted_row[p] = row;
    }
}

// ------------------------------------------------- W [128][64] -> WT bf16 --
__global__ __launch_bounds__(256) void wt_kernel(const float* __restrict__ W,
                                                 unsigned short* __restrict__ WT) {
    int idx = blockIdx.x * 256 + threadIdx.x;
    if (idx < IN_F * OUT_F) {
        int k = idx >> 6, n = idx & 63;
        WT[n * IN_F + k] = f2b(W[idx]);
    }
}

// --------------------------------------------------- h = bf16(x @ W) -------
// 256 thr / 64 rows per block. Xs,WsT bf16 in LDS, XOR-swizzled (G4:
// row-stride 256B would be a 32-way conflict on ds_read_b128).
// mfma_f32_16x16x32_bf16: A lane&15=m, k=(lane>>4)*8+i ; B lane&15=n, same k;
// D col=lane&15, row=(lane>>4)*4+reg  [m89/m92 verified mapping].
constexpr int GEMM_ROWS = 64;
__global__ __launch_bounds__(256) void gemm_kernel(const float* __restrict__ x,
                                                   const unsigned short* __restrict__ WT,
                                                   unsigned short* __restrict__ h) {
    __shared__ unsigned short Xs[GEMM_ROWS][IN_F];   // 16 KB
    __shared__ unsigned short Ws[OUT_F][IN_F];       // 16 KB (W^T: [n][k])
    const int tid = threadIdx.x;
    const int row0 = blockIdx.x * GEMM_ROWS;

    // stage W^T (global bf16 -> LDS, swizzled)
#pragma unroll
    for (int j = 0; j < 4; ++j) {
        int g  = tid + j * 256;            // 8-elem group id, 1024 groups
        int n  = g >> 4;
        int k8 = (g & 15) * 8;
        bf16x8 v = *(const bf16x8*)&WT[n * IN_F + k8];
        *(bf16x8*)&Ws[n][k8 ^ ((n & 7) << 3)] = v;
    }

    // stage X rows (f32 global -> bf16 LDS, swizzled). 4 threads per row.
    {
        int r    = tid >> 2;
        int grow = row0 + r;
        if (grow >= N_NODES) grow = N_NODES - 1;   // clamp (last block)
        int ks   = (tid & 3) * 32;
        const float4* xp = (const float4*)x + (long)grow * (IN_F / 4) + (ks >> 2);
        int sw = (r & 7) << 3;
#pragma unroll
        for (int j = 0; j < 8; ++j) {
            float4 xv = xp[j];
            unsigned int u0 = (unsigned int)f2b(xv.x) | ((unsigned int)f2b(xv.y) << 16);
            unsigned int u1 = (unsigned int)f2b(xv.z) | ((unsigned int)f2b(xv.w) << 16);
            uint2 p; p.x = u0; p.y = u1;
            *(uint2*)&Xs[r][(ks + j * 4) ^ sw] = p;
        }
    }
    __syncthreads();

    const int w    = tid >> 6;       // wave id: rows [w*16, w*16+16)
    const int lane = tid & 63;
    const int ml   = lane & 15;
    const int kg   = lane >> 4;      // 0..3

    const int rowA = w * 16 + ml;
    const int swA  = (rowA & 7) << 3;

    bf16x8 a[4];
#pragma unroll
    for (int kt = 0; kt < 4; ++kt)
        a[kt] = *(const bf16x8*)&Xs[rowA][(kt * 32 + kg * 8) ^ swA];

    f32x4 acc[4];
#pragma unroll
    for (int ct = 0; ct < 4; ++ct) acc[ct] = (f32x4)(0.0f);

#pragma unroll
    for (int ct = 0; ct < 4; ++ct) {
        int n  = ct * 16 + ml;
        int sw = (n & 7) << 3;
#pragma unroll
        for (int kt = 0; kt < 4; ++kt) {
            bf16x8 bv = *(const bf16x8*)&Ws[n][(kt * 32 + kg * 8) ^ sw];
            acc[ct] = __builtin_amdgcn_mfma_f32_16x16x32_bf16(a[kt], bv, acc[ct], 0, 0, 0);
        }
    }

    const int grow0 = row0 + w * 16 + kg * 4;
#pragma unroll
    for (int ct = 0; ct < 4; ++ct) {
#pragma unroll
        for (int i = 0; i < 4; ++i) {
            int r = grow0 + i;
            if (r < N_NODES)
                h[(long)r * OUT_F + ct * 16 + ml] = f2b(acc[ct][i]);
        }
    }
}

// ------------------------------------------------------ gather + epilogue --
// One wave per node. Two 32-lane halves each process alternate edges; lane sl
// owns features (2sl, 2sl+1) as one bf16x2 word. Cross-half reduce via
// shfl_xor(32). out written once, bias + self-loop fused. No f32 atomics.
__global__ __launch_bounds__(256) void gather_kernel(const int* __restrict__ sorted_row,
                                                     const int* __restrict__ offsets,
                                                     const float* __restrict__ dis,
                                                     const unsigned int* __restrict__ h2,
                                                     const float* __restrict__ b,
                                                     float* __restrict__ out) {
    int gtid = blockIdx.x * blockDim.x + threadIdx.x;
    int node = gtid >> 6;
    if (node >= N_NODES) return;
    int lane = threadIdx.x & 63;
    int half = lane >> 5;
    int sl   = lane & 31;

    int beg = offsets[node];
    int end = offsets[node + 1];
    float dc = dis[node];

    float ax = 0.0f, ay = 0.0f;
    for (int i = beg + half; i < end; i += 2) {
        int row  = sorted_row[i];                 // uniform within half-wave
        float wn = dis[row] * dc;
        unsigned int u = h2[row * 32 + sl];       // 128B per half, coalesced
        ax += wn * blo(u);
        ay += wn * bhi(u);
    }
    ax += __shfl_xor(ax, 32);
    ay += __shfl_xor(ay, 32);

    if (half == 0) {
        unsigned int us = h2[node * 32 + sl];
        float s = dc * dc;
        float2 bv = ((const float2*)b)[sl];
        float2 o;
        o.x = ax + bv.x + s * blo(us);
        o.y = ay + bv.y + s * bhi(us);
        ((float2*)out)[node * 32 + sl] = o;
    }
}

// ---------------------------------------------------------------------------
extern "C" void kernel_launch(void* const* d_in, const int* in_sizes, int n_in,
                              void* d_out, int out_size, void* d_ws, size_t ws_size,
                              hipStream_t stream) {
    const float* x   = (const float*)d_in[0];
    const int*   idx = (const int*)d_in[1];   // [2, E], delivered as int32
    const float* W   = (const float*)d_in[2];
    const float* b   = (const float*)d_in[3];
    float*       out = (float*)d_out;

    // workspace layout (16B alignment maintained)
    int*   cnt        = (int*)d_ws;                     // N
    float* dis        = (float*)(cnt + N_NODES);        // N
    int*   offsets    = (int*)(dis + N_NODES);          // N+4
    int*   cursor     = offsets + N_NODES + 4;          // N
    int*   bsums      = cursor + N_NODES;               // 392
    int*   bscan      = bsums + 392;                    // 392
    int*   scanned    = bscan + 392;                    // N
    int*   sorted_row = scanned + N_NODES;              // E
    unsigned short* WT = (unsigned short*)(sorted_row + N_EDGES);  // 8192
    unsigned short* hb = WT + IN_F * OUT_F;             // N*64 bf16

    hipMemsetAsync(cnt, 0, N_NODES * sizeof(int), stream);
    count_kernel<<<2048, 256, 0, stream>>>(idx + N_EDGES, cnt);
    dis_kernel<<<(N_NODES + 255) / 256, 256, 0, stream>>>(cnt, dis);
    scanA_kernel<<<N_SCANB, SCAN_B, 0, stream>>>(cnt, scanned, bsums);
    scanB_kernel<<<1, 512, 0, stream>>>(bsums, bscan);
    scanC_kernel<<<(N_NODES + 255) / 256, 256, 0, stream>>>(scanned, bscan,
                                                            offsets, cursor);
    fill_kernel<<<2048, 256, 0, stream>>>(idx, cursor, sorted_row);
    wt_kernel<<<(IN_F * OUT_F + 255) / 256, 256, 0, stream>>>(W, WT);
    gemm_kernel<<<(N_NODES + GEMM_ROWS - 1) / GEMM_ROWS, 256, 0, stream>>>(x, WT, hb);
    gather_kernel<<<(N_NODES * 64 + 255) / 256, 256, 0, stream>>>(
        sorted_row, offsets, dis, (const unsigned int*)hb, b, out);
}

// Round 6
// 247.362 us; speedup vs baseline: 2.2902x; 1.6103x over previous
//
#include <hip/hip_runtime.h>
#include <hip/hip_bf16.h>

// GCNConv, gather formulation. History:
//  R1: scatter f32 atomics (400MB EA write-through)        566us
//  R3: CSR gather (random-atomic fill)                     500us
//  R5: bf16 h + MFMA gemm                                  398us  (fill=135us top)
//  R6: deterministic bucket counting-sort replaces count/scan/fill
//      (random 4B scatter -> dense per-bucket runs, LDS-local CSR).
constexpr int N_NODES = 100000;
constexpr int IN_F    = 128;
constexpr int OUT_F   = 64;
constexpr int N_EDGES = 1600000;

constexpr int NPB     = 128;                    // nodes per bucket (col>>7)
constexpr int NB      = (N_NODES + NPB - 1) / NPB;  // 782 buckets
constexpr int B_HIST  = 512;                    // blocks in hist/scatter pass
constexpr int EPB     = N_EDGES / B_HIST;       // 3125 edges per block
constexpr int STAGE_CAP = 2816;                 // bucket LDS stage (mean 2048, +17 sigma)

typedef short bf16x8 __attribute__((ext_vector_type(8)));
typedef float f32x4  __attribute__((ext_vector_type(4)));

static __device__ __forceinline__ unsigned short f2b(float f) {
    __hip_bfloat16 h = __float2bfloat16(f);
    return *reinterpret_cast<unsigned short*>(&h);
}
static __device__ __forceinline__ float blo(unsigned int u) {
    return __uint_as_float(u << 16);
}
static __device__ __forceinline__ float bhi(unsigned int u) {
    return __uint_as_float(u & 0xffff0000u);
}

// --------------------------------------------- K1: per-block bucket histogram
__global__ __launch_bounds__(256) void hist_kernel(const int* __restrict__ col,
                                                   int* __restrict__ hist_g) {
    __shared__ int hist[NB];
    for (int i = threadIdx.x; i < NB; i += 256) hist[i] = 0;
    __syncthreads();
    const int beg = blockIdx.x * EPB, end = beg + EPB;
    for (int e = beg + threadIdx.x; e < end; e += 256)
        atomicAdd(&hist[col[e] >> 7], 1);
    __syncthreads();
    for (int i = threadIdx.x; i < NB; i += 256)
        hist_g[i * B_HIST + blockIdx.x] = hist[i];
}

// ------------------- K2a: per-bucket scan over blocks (in-place) + bin totals
__global__ __launch_bounds__(512) void scanbins_kernel(int* __restrict__ hist_g,
                                                       int* __restrict__ binTotal) {
    __shared__ int s[B_HIST];
    const int bin = blockIdx.x, t = threadIdx.x;
    int v = hist_g[bin * B_HIST + t];
    s[t] = v;
    __syncthreads();
#pragma unroll
    for (int off = 1; off < B_HIST; off <<= 1) {
        int u = (t >= off) ? s[t - off] : 0;
        __syncthreads();
        s[t] += u;
        __syncthreads();
    }
    hist_g[bin * B_HIST + t] = s[t] - v;     // exclusive within bin
    if (t == B_HIST - 1) binTotal[bin] = s[t];
}

// ----------------------------------- K2b: scan bucket totals -> bucket starts
__global__ __launch_bounds__(1024) void scanoff_kernel(const int* __restrict__ binTotal,
                                                       int* __restrict__ binStart,
                                                       int* __restrict__ offsets) {
    __shared__ int s[1024];
    const int t = threadIdx.x;
    int v = (t < NB) ? binTotal[t] : 0;
    s[t] = v;
    __syncthreads();
#pragma unroll
    for (int off = 1; off < 1024; off <<= 1) {
        int u = (t >= off) ? s[t - off] : 0;
        __syncthreads();
        s[t] += u;
        __syncthreads();
    }
    if (t < NB) binStart[t] = s[t] - v;
    if (t == 0) {
        binStart[NB] = N_EDGES;
        offsets[N_NODES] = N_EDGES;
    }
}

// ------------- K3: bucket-partition pairs (deterministic runs, no g-atomics)
__global__ __launch_bounds__(256) void scatter_kernel(const int* __restrict__ eidx,
                                                      const int* __restrict__ hist_g,
                                                      const int* __restrict__ binStart,
                                                      uint2* __restrict__ pairs) {
    __shared__ int cur[NB];
    for (int i = threadIdx.x; i < NB; i += 256)
        cur[i] = binStart[i] + hist_g[i * B_HIST + blockIdx.x];
    __syncthreads();
    const int beg = blockIdx.x * EPB, end = beg + EPB;
    for (int e = beg + threadIdx.x; e < end; e += 256) {
        int row = eidx[e];
        int col = eidx[N_EDGES + e];
        int p = atomicAdd(&cur[col >> 7], 1);     // LDS atomic only
        pairs[p] = make_uint2((unsigned)col, (unsigned)row);
    }
}

// ------ K4: per-bucket CSR finalize: offsets, dis, sorted_row (all dense) ---
__global__ __launch_bounds__(256) void finalize_kernel(const uint2* __restrict__ pairs,
                                                       const int* __restrict__ binStart,
                                                       int* __restrict__ offsets,
                                                       float* __restrict__ dis,
                                                       int* __restrict__ sorted_row) {
    __shared__ uint2 st[STAGE_CAP];
    __shared__ int cnt[NPB], s[NPB], curs[NPB];
    const int b = blockIdx.x, t = threadIdx.x;
    const int beg = binStart[b], end = binStart[b + 1];
    const int n0 = b << 7;
    const int nn = min(NPB, N_NODES - n0);
    const int size = end - beg;

    for (int i = t; i < NPB; i += 256) cnt[i] = 0;
    __syncthreads();
    for (int i = t; i < size; i += 256) {
        uint2 p = pairs[beg + i];
        if (i < STAGE_CAP) st[i] = p;
        atomicAdd(&cnt[p.x & (NPB - 1)], 1);
    }
    __syncthreads();
    if (t < NPB) s[t] = cnt[t];
    __syncthreads();
#pragma unroll
    for (int off = 1; off < NPB; off <<= 1) {
        int u = (t < NPB && t >= off) ? s[t - off] : 0;
        __syncthreads();
        if (t < NPB) s[t] += u;
        __syncthreads();
    }
    if (t < NPB) {
        int ex = s[t] - cnt[t];
        curs[t] = ex;
        if (t < nn) {
            offsets[n0 + t] = beg + ex;
            dis[n0 + t] = rsqrtf((float)cnt[t] + 1.0f);
        }
    }
    __syncthreads();
    for (int i = t; i < size; i += 256) {
        uint2 p = (i < STAGE_CAP) ? st[i] : pairs[beg + i];
        int q = atomicAdd(&curs[p.x & (NPB - 1)], 1);
        sorted_row[beg + q] = (int)p.y;            // dense ~8KB region
    }
}

// ------------------------------------------------- W [128][64] -> WT bf16 --
__global__ __launch_bounds__(256) void wt_kernel(const float* __restrict__ W,
                                                 unsigned short* __restrict__ WT) {
    int idx = blockIdx.x * 256 + threadIdx.x;
    if (idx < IN_F * OUT_F) {
        int k = idx >> 6, n = idx & 63;
        WT[n * IN_F + k] = f2b(W[idx]);
    }
}

// --------------------------------------------------- h = bf16(x @ W) -------
// mfma_f32_16x16x32_bf16; LDS XOR-swizzled bf16 tiles (verified R5).
constexpr int GEMM_ROWS = 64;
__global__ __launch_bounds__(256) void gemm_kernel(const float* __restrict__ x,
                                                   const unsigned short* __restrict__ WT,
                                                   unsigned short* __restrict__ h) {
    __shared__ unsigned short Xs[GEMM_ROWS][IN_F];   // 16 KB
    __shared__ unsigned short Ws[OUT_F][IN_F];       // 16 KB (W^T: [n][k])
    const int tid = threadIdx.x;
    const int row0 = blockIdx.x * GEMM_ROWS;

#pragma unroll
    for (int j = 0; j < 4; ++j) {
        int g  = tid + j * 256;
        int n  = g >> 4;
        int k8 = (g & 15) * 8;
        bf16x8 v = *(const bf16x8*)&WT[n * IN_F + k8];
        *(bf16x8*)&Ws[n][k8 ^ ((n & 7) << 3)] = v;
    }
    {
        int r    = tid >> 2;
        int grow = row0 + r;
        if (grow >= N_NODES) grow = N_NODES - 1;
        int ks   = (tid & 3) * 32;
        const float4* xp = (const float4*)x + (long)grow * (IN_F / 4) + (ks >> 2);
        int sw = (r & 7) << 3;
#pragma unroll
        for (int j = 0; j < 8; ++j) {
            float4 xv = xp[j];
            unsigned int u0 = (unsigned int)f2b(xv.x) | ((unsigned int)f2b(xv.y) << 16);
            unsigned int u1 = (unsigned int)f2b(xv.z) | ((unsigned int)f2b(xv.w) << 16);
            uint2 p; p.x = u0; p.y = u1;
            *(uint2*)&Xs[r][(ks + j * 4) ^ sw] = p;
        }
    }
    __syncthreads();

    const int w    = tid >> 6;
    const int lane = tid & 63;
    const int ml   = lane & 15;
    const int kg   = lane >> 4;

    const int rowA = w * 16 + ml;
    const int swA  = (rowA & 7) << 3;

    bf16x8 a[4];
#pragma unroll
    for (int kt = 0; kt < 4; ++kt)
        a[kt] = *(const bf16x8*)&Xs[rowA][(kt * 32 + kg * 8) ^ swA];

    f32x4 acc[4];
#pragma unroll
    for (int ct = 0; ct < 4; ++ct) acc[ct] = (f32x4)(0.0f);

#pragma unroll
    for (int ct = 0; ct < 4; ++ct) {
        int n  = ct * 16 + ml;
        int sw = (n & 7) << 3;
#pragma unroll
        for (int kt = 0; kt < 4; ++kt) {
            bf16x8 bv = *(const bf16x8*)&Ws[n][(kt * 32 + kg * 8) ^ sw];
            acc[ct] = __builtin_amdgcn_mfma_f32_16x16x32_bf16(a[kt], bv, acc[ct], 0, 0, 0);
        }
    }

    const int grow0 = row0 + w * 16 + kg * 4;
#pragma unroll
    for (int ct = 0; ct < 4; ++ct) {
#pragma unroll
        for (int i = 0; i < 4; ++i) {
            int r = grow0 + i;
            if (r < N_NODES)
                h[(long)r * OUT_F + ct * 16 + ml] = f2b(acc[ct][i]);
        }
    }
}

// ------------------------------------------------------ gather + epilogue --
__global__ __launch_bounds__(256) void gather_kernel(const int* __restrict__ sorted_row,
                                                     const int* __restrict__ offsets,
                                                     const float* __restrict__ dis,
                                                     const unsigned int* __restrict__ h2,
                                                     const float* __restrict__ b,
                                                     float* __restrict__ out) {
    int gtid = blockIdx.x * blockDim.x + threadIdx.x;
    int node = gtid >> 6;
    if (node >= N_NODES) return;
    int lane = threadIdx.x & 63;
    int half = lane >> 5;
    int sl   = lane & 31;

    int beg = offsets[node];
    int end = offsets[node + 1];
    float dc = dis[node];

    float ax = 0.0f, ay = 0.0f;
    for (int i = beg + half; i < end; i += 2) {
        int row  = sorted_row[i];
        float wn = dis[row] * dc;
        unsigned int u = h2[row * 32 + sl];
        ax += wn * blo(u);
        ay += wn * bhi(u);
    }
    ax += __shfl_xor(ax, 32);
    ay += __shfl_xor(ay, 32);

    if (half == 0) {
        unsigned int us = h2[node * 32 + sl];
        float sc = dc * dc;
        float2 bv = ((const float2*)b)[sl];
        float2 o;
        o.x = ax + bv.x + sc * blo(us);
        o.y = ay + bv.y + sc * bhi(us);
        ((float2*)out)[node * 32 + sl] = o;
    }
}

// ---------------------------------------------------------------------------
extern "C" void kernel_launch(void* const* d_in, const int* in_sizes, int n_in,
                              void* d_out, int out_size, void* d_ws, size_t ws_size,
                              hipStream_t stream) {
    const float* x   = (const float*)d_in[0];
    const int*   idx = (const int*)d_in[1];   // [2, E], delivered as int32
    const float* W   = (const float*)d_in[2];
    const float* b   = (const float*)d_in[3];
    float*       out = (float*)d_out;

    // workspace layout (ints; pairs first for 8B alignment)
    int* p          = (int*)d_ws;
    uint2* pairs    = (uint2*)p;            p += 2 * N_EDGES;       // 12.8 MB
    int* hist_g     = p;                    p += NB * B_HIST;       // 1.6 MB
    int* binTotal   = p;                    p += 784;
    int* binStart   = p;                    p += 784;
    int* offsets    = p;                    p += N_NODES + 4;
    float* dis      = (float*)p;            p += N_NODES;
    int* sorted_row = p;                    p += N_EDGES;           // 6.4 MB
    unsigned short* WT = (unsigned short*)p; p += IN_F * OUT_F / 2;
    unsigned short* hb = (unsigned short*)p;                        // 12.8 MB

    hist_kernel<<<B_HIST, 256, 0, stream>>>(idx + N_EDGES, hist_g);
    scanbins_kernel<<<NB, 512, 0, stream>>>(hist_g, binTotal);
    scanoff_kernel<<<1, 1024, 0, stream>>>(binTotal, binStart, offsets);
    scatter_kernel<<<B_HIST, 256, 0, stream>>>(idx, hist_g, binStart, pairs);
    wt_kernel<<<(IN_F * OUT_F + 255) / 256, 256, 0, stream>>>(W, WT);
    gemm_kernel<<<(N_NODES + GEMM_ROWS - 1) / GEMM_ROWS, 256, 0, stream>>>(x, WT, hb);
    finalize_kernel<<<NB, 256, 0, stream>>>(pairs, binStart, offsets, dis, sorted_row);
    gather_kernel<<<(N_NODES * 64 + 255) / 256, 256, 0, stream>>>(
        sorted_row, offsets, dis, (const unsigned int*)hb, b, out);
}